// Round 14
// baseline (125.464 us; speedup 1.0000x reference)
//
#include <hip/hip_runtime.h>

#define B_SZ 2
#define T_SZ 2048
#define DM   1024
#define NH   16
#define DH   64

typedef __attribute__((ext_vector_type(8))) short bf16x8;
typedef __attribute__((ext_vector_type(4))) float f32x4;
typedef __attribute__((ext_vector_type(4))) unsigned int u32x4;
typedef __attribute__((ext_vector_type(4))) unsigned short u16x4;

__device__ __forceinline__ unsigned short f2bf(float f) {
  unsigned u = __builtin_bit_cast(unsigned, f);
  u += 0x7FFFu + ((u >> 16) & 1u);
  return (unsigned short)(u >> 16);
}
__device__ __forceinline__ unsigned packbf(float lo, float hi) {
  return (unsigned)f2bf(lo) | ((unsigned)f2bf(hi) << 16);
}

// stage 16 f32 -> 16 bf16 into LDS
__device__ __forceinline__ void stage16(const float* src, unsigned short* dst) {
  const f32x4* ps = (const f32x4*)src;
  f32x4 v0 = ps[0], v1 = ps[1], v2 = ps[2], v3 = ps[3];
  u32x4 w0, w1;
  w0[0] = packbf(v0[0], v0[1]); w0[1] = packbf(v0[2], v0[3]);
  w0[2] = packbf(v1[0], v1[1]); w0[3] = packbf(v1[2], v1[3]);
  w1[0] = packbf(v2[0], v2[1]); w1[1] = packbf(v2[2], v2[3]);
  w1[2] = packbf(v3[0], v3[1]); w1[3] = packbf(v3[2], v3[3]);
  *(u32x4*)dst = w0;
  *(u32x4*)(dst + 8) = w1;
}

// async global->LDS, 16B per lane
__device__ __forceinline__ void gload16(const unsigned short* g, unsigned short* l) {
  __builtin_amdgcn_global_load_lds(
      (const __attribute__((address_space(1))) unsigned int*)(const void*)g,
      (__attribute__((address_space(3))) unsigned int*)(void*)l, 16, 0, 0);
}

__device__ __forceinline__ void cvt16(const float* s, unsigned short* d, float scale) {
  const f32x4* ps = (const f32x4*)s;
  f32x4 v0 = ps[0] * scale, v1 = ps[1] * scale, v2 = ps[2] * scale, v3 = ps[3] * scale;
  u32x4 w0, w1;
  w0[0] = packbf(v0[0], v0[1]); w0[1] = packbf(v0[2], v0[3]);
  w0[2] = packbf(v1[0], v1[1]); w0[3] = packbf(v1[2], v1[3]);
  w1[0] = packbf(v2[0], v2[1]); w1[1] = packbf(v2[2], v2[3]);
  w1[2] = packbf(v3[0], v3[1]); w1[3] = packbf(v3[2], v3[3]);
  *(u32x4*)d = w0;
  *(u32x4*)(d + 8) = w1;
}

// All six f32->bf16 conversions in ONE launch.
__global__ __launch_bounds__(256) void cvt_all(
    const float* __restrict__ wq, const float* __restrict__ wk,
    const float* __restrict__ wv, const float* __restrict__ wo,
    const float* __restrict__ qr, const float* __restrict__ kvr,
    unsigned short* __restrict__ dq, unsigned short* __restrict__ dk,
    unsigned short* __restrict__ dv, unsigned short* __restrict__ dwo,
    unsigned short* __restrict__ dqr, unsigned short* __restrict__ dkvr,
    float qscale) {
  const int bid = blockIdx.x;
  const float* s; unsigned short* d; float sc = 1.0f; int off;
  if (bid < 1024) {
    const int which = bid >> 8; off = bid & 255;
    s = (which == 0) ? wq : (which == 1) ? wk : (which == 2) ? wv : wo;
    d = (which == 0) ? dq : (which == 1) ? dk : (which == 2) ? dv : dwo;
    if (which == 0) sc = qscale;
  } else {
    const int which = (bid - 1024) >> 10; off = (bid - 1024) & 1023;
    s = which ? kvr : qr;
    d = which ? dkvr : dqr;
  }
  const int i = (off * 256 + threadIdx.x) * 16;
  cvt16(s + i, d + i, sc);
}

__global__ __launch_bounds__(256) void cvt_w4(
    const float* __restrict__ s0, const float* __restrict__ s1,
    const float* __restrict__ s2, const float* __restrict__ s3,
    unsigned short* __restrict__ d0, unsigned short* __restrict__ d1,
    unsigned short* __restrict__ d2, unsigned short* __restrict__ d3,
    float qscale) {
  const int y = blockIdx.y;
  const float* s = (y == 0) ? s0 : (y == 1) ? s1 : (y == 2) ? s2 : s3;
  unsigned short* d = (y == 0) ? d0 : (y == 1) ? d1 : (y == 2) ? d2 : d3;
  const float sc = (y == 0) ? qscale : 1.0f;
  const int i = (blockIdx.x * 256 + threadIdx.x) * 16;
  cvt16(s + i, d + i, sc);
}

// C = A * B^T, tile 128x64, BK=32, MFMA 16x16x32 bf16.
// Flat grid + XCD-chunked swizzle (R6/R8/R10/R12 proven version).
template<int AMODE, int BMODE, int CMODE>
__global__ __launch_bounds__(256) void gemm2(
    const void* __restrict__ A0, const void* __restrict__ A1, int lda,
    const void* __restrict__ B0, const void* __restrict__ B1, int ldb, long bZ,
    void* __restrict__ C0, void* __restrict__ C1, int K, int nx, int ny) {
  __shared__ unsigned short As[128 * 32];
  __shared__ unsigned short Bs[64 * 32];
  const int tid = threadIdx.x, lane = tid & 63, w = tid >> 6;
  const int wm = w >> 1, wn = w & 1;
  const int l15 = lane & 15, lg = lane >> 4;

  const int cpx = gridDim.x >> 3;
  const int flat = (blockIdx.x & 7) * cpx + (blockIdx.x >> 3);
  const int nbk = flat % nx;
  const int rest = flat / nx;
  const int mbk = rest % ny;
  const int z = rest / ny;
  const int mblk = mbk * 128, nblk = nbk * 64;

  const void* Ap; const void* Bp; void* Cp;
  long aoff = 0; int zb = 0, zs = 0;
  if constexpr (CMODE == 0) {
    Ap = z ? A1 : A0; Bp = z ? B1 : B0; Cp = z ? C1 : C0;
  } else if constexpr (CMODE == 2) {
    Ap = A0; Cp = C0;
    if constexpr (BMODE == 1) Bp = (const void*)((const unsigned short*)B0 + (long)z * bZ);
    else                      Bp = (const void*)((const float*)B0 + (long)z * bZ);
  } else {
    Ap = A0; Bp = B0; Cp = C0;
    zb = z >> 1; zs = z & 1;
    aoff = (long)zb * 2097152 + (long)zs * 1024;
  }

  f32x4 acc[4][2];
#pragma unroll
  for (int i = 0; i < 4; i++)
#pragma unroll
    for (int j = 0; j < 2; j++) acc[i][j] = (f32x4){0.f, 0.f, 0.f, 0.f};

  const int asr = tid >> 1, asc = (tid & 1) * 16;
  const int agr = w * 32 + (lane >> 2), agc = (lane & 3) * 8;
  const int bgr = w * 16 + (lane >> 2), bgc = (lane & 3) * 8;

  for (int k0 = 0; k0 < K; k0 += 32) {
    if constexpr (AMODE == 0) {
      stage16((const float*)Ap + (long)(mblk + asr) * lda + k0 + asc, &As[asr * 32 + asc]);
    } else {
      const unsigned short* Ab = (const unsigned short*)Ap + aoff;
      gload16(Ab + (long)(mblk + agr) * lda + k0 + agc, &As[w * 1024]);
      gload16(Ab + (long)(mblk + agr + 16) * lda + k0 + agc, &As[w * 1024 + 512]);
    }
    if constexpr (BMODE == 0) {
      if (tid < 128)
        stage16((const float*)Bp + (long)(nblk + asr) * ldb + k0 + asc, &Bs[asr * 32 + asc]);
    } else {
      gload16((const unsigned short*)Bp + (long)(nblk + bgr) * ldb + k0 + bgc, &Bs[w * 512]);
    }
    __syncthreads();

    bf16x8 af[4], bfr[2];
#pragma unroll
    for (int mi = 0; mi < 4; mi++)
      af[mi] = *(const bf16x8*)&As[(wm * 64 + mi * 16 + l15) * 32 + lg * 8];
#pragma unroll
    for (int nj = 0; nj < 2; nj++)
      bfr[nj] = *(const bf16x8*)&Bs[(wn * 32 + nj * 16 + l15) * 32 + lg * 8];
#pragma unroll
    for (int mi = 0; mi < 4; mi++)
#pragma unroll
      for (int nj = 0; nj < 2; nj++)
        acc[mi][nj] = __builtin_amdgcn_mfma_f32_16x16x32_bf16(af[mi], bfr[nj], acc[mi][nj], 0, 0, 0);
    __syncthreads();
  }

#pragma unroll
  for (int mi = 0; mi < 4; mi++) {
#pragma unroll
    for (int nj = 0; nj < 2; nj++) {
#pragma unroll
      for (int r = 0; r < 4; r++) {
        const int i = mblk + wm * 64 + mi * 16 + lg * 4 + r;
        const int n = nblk + wn * 32 + nj * 16 + l15;
        const float v = acc[mi][nj][r];
        if constexpr (CMODE == 0) {
          const int b = i >> 11, t = i & 2047, h = n >> 6, d = n & 63;
          ((unsigned short*)Cp)[((long)(b * NH + h) * T_SZ + t) * DH + d] = f2bf(v);
        } else if constexpr (CMODE == 2) {
          ((unsigned short*)Cp)[(long)z * 2097152 + (long)i * 2048 + n] = f2bf(v);
        } else {
          ((float*)Cp)[(long)zb * T_SZ * DM + (long)(2 * i + zs) * DM + n] = v;
        }
      }
    }
  }
}

// Flash attention, causal + kv padding mask. Uniform-17 schedule + LDS bitmask
// + no-max softmax + trunc P->bf16 + row-sum l via MFMA-with-ones.
// (R13 proven body, unchanged.)
__global__ __launch_bounds__(512) void attn3(const unsigned short* __restrict__ Qh,
                                             const unsigned short* __restrict__ Kh,
                                             const unsigned short* __restrict__ Vt,
                                             const int* __restrict__ kmask,
                                             unsigned short* __restrict__ Zt) {
  __shared__ unsigned short lds_kv[2][2][64][72];  // [group][K/V][row][col] 36,864 B
  __shared__ unsigned short lds_p[8][16][72];      // per-wave P buffer      18,432 B
  __shared__ unsigned long long bmask[32];         // per-64-key-tile kv mask
  const int tid = threadIdx.x, lane = tid & 63, w = tid >> 6;
  const int l15 = lane & 15, lg = lane >> 4;
  const int g = w >> 2, sw = w & 3;
  const int wg = blockIdx.x;
  const int xcd = wg & 7, lin = wg >> 3;           // lin in 0..63
  const int bh = xcd * 4 + (lin >> 4);
  const int p = lin & 15;
  const int b = bh >> 4, h = bh & 15;
  const int q0a = (31 - p) * 64;
  const int q0b = p * 64;
  const unsigned short* Qb = Qh + ((long)bh << 17);
  const unsigned short* Kb = Kh + ((long)bh << 17);
  const unsigned short* Vtb = Vt + ((long)(b * DM + h * DH)) * T_SZ;
  const long zbase = (long)(b * DM + h * DH) * T_SZ;

  // bf16 1.0 fragment for row-sum-via-MFMA
  const bf16x8 ones = {0x3F80, 0x3F80, 0x3F80, 0x3F80, 0x3F80, 0x3F80, 0x3F80, 0x3F80};

  // precompute kv-mask bitmask: wave w covers tiles w*4..w*4+3
#pragma unroll
  for (int k = 0; k < 4; k++) {
    const int ti = w * 4 + k;
    const int mk = kmask[b * T_SZ + ti * 64 + lane];
    const unsigned long long bm = __ballot(mk != 0);
    if (lane == 0) bmask[ti] = bm;
  }

  int q0 = g ? q0b : q0a;
  bf16x8 qf0, qf1;
  {
    const int qra = q0 + sw * 16 + l15;
    qf0 = *(const bf16x8*)(Qb + ((long)qra << 6) + lg * 8);
    qf1 = *(const bf16x8*)(Qb + ((long)qra << 6) + 32 + lg * 8);
  }
  int qc0 = q0 + sw * 16 + lg * 4;

  f32x4 o[4];
  float lr[4];
#pragma unroll
  for (int i = 0; i < 4; i++) {
    o[i] = (f32x4){0.f, 0.f, 0.f, 0.f};
    lr[i] = 0.f;
  }

  // staging: quarter = {K_g0, V_g0, K_g1, V_g1}; 2 thr/row, 64 B each
  const int quarter = tid >> 7, sg = quarter >> 1, skv = quarter & 1;
  const int srow = (tid & 127) >> 1;
  const int soff = (tid & 1) * 32;
  const unsigned short* kp = Kb + ((long)srow << 6) + soff;
  const unsigned short* vp = Vtb + (long)srow * T_SZ + soff;

  u32x4 pr0, pr1, pr2, pr3;
  auto issue = [&](int it) {
    int j0s;
    if (sg == 0) j0s = it * 64;
    else j0s = (it <= p) ? it * 64 : ((it < 16) ? (16 + it - p) * 64 : 0);
    const u32x4* s = (const u32x4*)(skv ? (vp + j0s) : (kp + ((long)j0s << 6)));
    pr0 = s[0]; pr1 = s[1]; pr2 = s[2]; pr3 = s[3];
  };

  auto writeZ = [&](const f32x4* oo, const float* ll, int qq) {
    float inv[4];
#pragma unroll
    for (int r = 0; r < 4; r++) inv[r] = (ll[r] > 0.f) ? (1.f / ll[r]) : 0.f;
#pragma unroll
    for (int nb = 0; nb < 4; nb++) {
      u16x4 pk;
#pragma unroll
      for (int r = 0; r < 4; r++) pk[r] = f2bf(oo[nb][r] * inv[r]);
      *(u16x4*)&Zt[zbase + (long)(nb * 16 + l15) * T_SZ + qq] = pk;
    }
  };

  issue(0);
  for (int it = 0; it < 17; ++it) {
    __syncthreads();
    *(u32x4*)&lds_kv[sg][skv][srow][soff] = pr0;
    *(u32x4*)&lds_kv[sg][skv][srow][soff + 8] = pr1;
    *(u32x4*)&lds_kv[sg][skv][srow][soff + 16] = pr2;
    *(u32x4*)&lds_kv[sg][skv][srow][soff + 24] = pr3;
    __syncthreads();
    if (it + 1 < 17) issue(it + 1);

    // group-1 phase switch: seg-b complete -> emit; continue on seg-a tail
    if (g == 1 && it == p + 1) {
      writeZ(o, lr, qc0);
#pragma unroll
      for (int i = 0; i < 4; i++) {
        o[i] = (f32x4){0.f, 0.f, 0.f, 0.f};
        lr[i] = 0.f;
      }
      q0 = q0a;
      const int qra = q0 + sw * 16 + l15;
      qf0 = *(const bf16x8*)(Qb + ((long)qra << 6) + lg * 8);
      qf1 = *(const bf16x8*)(Qb + ((long)qra << 6) + 32 + lg * 8);
      qc0 = q0 + sw * 16 + lg * 4;
    }

    int j0 = it * 64;
    bool valid = true;
    if (g == 1) {
      if (it <= p) j0 = it * 64;
      else if (it < 16) j0 = (16 + it - p) * 64;
      else valid = false;
    }

    if (valid) {
      const unsigned long long kvm = bmask[j0 >> 6];

      f32x4 sa[4];
      __builtin_amdgcn_s_setprio(1);
#pragma unroll
      for (int cb = 0; cb < 4; cb++) {
        bf16x8 kf0 = *(const bf16x8*)&lds_kv[g][0][cb * 16 + l15][lg * 8];
        bf16x8 kf1 = *(const bf16x8*)&lds_kv[g][0][cb * 16 + l15][32 + lg * 8];
        f32x4 t = {0.f, 0.f, 0.f, 0.f};
        t = __builtin_amdgcn_mfma_f32_16x16x32_bf16(qf0, kf0, t, 0, 0, 0);
        t = __builtin_amdgcn_mfma_f32_16x16x32_bf16(qf1, kf1, t, 0, 0, 0);
        sa[cb] = t;
      }
      __builtin_amdgcn_s_setprio(0);

      const bool diag = (j0 == q0);
      if (diag || kvm != ~0ull) {
#pragma unroll
        for (int cb = 0; cb < 4; cb++) {
          const int kk = cb * 16 + l15;
          const bool mk2 = (kvm >> kk) & 1ull;
#pragma unroll
          for (int r = 0; r < 4; r++) {
            const bool ok = mk2 && (!diag || (j0 + kk <= qc0 + r));
            sa[cb][r] = ok ? sa[cb][r] : -1e30f;
          }
        }
      }
      // exp2 + truncating bf16 convert + P store (no max-subtraction needed)
#pragma unroll
      for (int cb = 0; cb < 4; cb++)
#pragma unroll
        for (int r = 0; r < 4; r++) {
          const float pe = __builtin_amdgcn_exp2f(sa[cb][r]);
          lds_p[w][lg * 4 + r][cb * 16 + l15] =
              (unsigned short)(__builtin_bit_cast(unsigned, pe) >> 16);
        }
      bf16x8 pf0 = *(const bf16x8*)&lds_p[w][l15][lg * 8];
      bf16x8 pf1 = *(const bf16x8*)&lds_p[w][l15][32 + lg * 8];

      __builtin_amdgcn_s_setprio(1);
      // l += row-sum(P) via MFMA with ones-B (frees VALU, feeds idle MFMA pipe)
      f32x4 ls = {0.f, 0.f, 0.f, 0.f};
      ls = __builtin_amdgcn_mfma_f32_16x16x32_bf16(pf0, ones, ls, 0, 0, 0);
      ls = __builtin_amdgcn_mfma_f32_16x16x32_bf16(pf1, ones, ls, 0, 0, 0);
#pragma unroll
      for (int nb = 0; nb < 4; nb++) {
        bf16x8 vf0 = *(const bf16x8*)&lds_kv[g][1][nb * 16 + l15][lg * 8];
        bf16x8 vf1 = *(const bf16x8*)&lds_kv[g][1][nb * 16 + l15][32 + lg * 8];
        f32x4 t = o[nb];
        t = __builtin_amdgcn_mfma_f32_16x16x32_bf16(pf0, vf0, t, 0, 0, 0);
        t = __builtin_amdgcn_mfma_f32_16x16x32_bf16(pf1, vf1, t, 0, 0, 0);
        o[nb] = t;
      }
      __builtin_amdgcn_s_setprio(0);
#pragma unroll
      for (int r = 0; r < 4; r++) lr[r] += ls[r];
    }
  }

  // ---- merge seg-a partials: plain sum (no-max softmax) ----
  __syncthreads();
  float* obuf = (float*)&lds_kv[0][0][0][0];   // [4 waves][16 rows][stride 65]
  float* mlb  = obuf + 4 * 16 * 65;            // [4 waves][16] l values
  if (g == 1) {
#pragma unroll
    for (int nb = 0; nb < 4; nb++)
#pragma unroll
      for (int r = 0; r < 4; r++)
        obuf[(sw * 16 + lg * 4 + r) * 65 + nb * 16 + l15] = o[nb][r];
    if (l15 == 0) {
#pragma unroll
      for (int r = 0; r < 4; r++)
        mlb[sw * 16 + lg * 4 + r] = lr[r];
    }
  }
  __syncthreads();
  if (g == 0) {
    float inv[4];
#pragma unroll
    for (int r = 0; r < 4; r++) {
      const float ls2 = lr[r] + mlb[sw * 16 + lg * 4 + r];
      inv[r] = (ls2 > 0.f) ? (1.f / ls2) : 0.f;
    }
#pragma unroll
    for (int nb = 0; nb < 4; nb++) {
      u16x4 pk;
#pragma unroll
      for (int r = 0; r < 4; r++) {
        const float o1 = obuf[(sw * 16 + lg * 4 + r) * 65 + nb * 16 + l15];
        pk[r] = f2bf((o[nb][r] + o1) * inv[r]);
      }
      *(u16x4*)&Zt[zbase + (long)(nb * 16 + l15) * T_SZ + qc0] = pk;
    }
  }
}

extern "C" void kernel_launch(void* const* d_in, const int* in_sizes, int n_in,
                              void* d_out, int out_size, void* d_ws, size_t ws_size,
                              hipStream_t stream) {
  const float* q_raw  = (const float*)d_in[0];
  const float* kv_raw = (const float*)d_in[1];
  const int*   kmask  = (const int*)d_in[2];
  const float* Wq = (const float*)d_in[3];
  const float* Wk = (const float*)d_in[4];
  const float* Wv = (const float*)d_in[5];
  const float* Wo = (const float*)d_in[6];
  float* out = (float*)d_out;

  // 1/sqrt(64) * log2(e): softmax runs in exp2 domain
  const float QSCALE = 0.125f * 1.44269504088896f;

  unsigned short* ws = (unsigned short*)d_ws;
  unsigned short* Qh = ws;                     // [32][2048][64] bf16  8 MB
  unsigned short* Kh = ws + 4194304;           //                      8 MB
  unsigned short* Vt = ws + 8388608;           // [2][1024][2048]      8 MB
  unsigned short* Zt = ws + 12582912;          // [2][1024][2048]      8 MB
  const bool full = ws_size >= (size_t)58720256;

  if (full) {
    unsigned short* wqb = ws + 16777216;
    unsigned short* wkb = ws + 17825792;
    unsigned short* wvb = ws + 18874368;
    unsigned short* wob = ws + 19922944;
    unsigned short* qb  = ws + 20971520;
    unsigned short* kvb = ws + 25165824;
    cvt_all<<<dim3(3072), 256, 0, stream>>>(Wq, Wk, Wv, Wo, q_raw, kv_raw,
                                            wqb, wkb, wvb, wob, qb, kvb, QSCALE);
    gemm2<1, 1, 0><<<dim3(1024), 256, 0, stream>>>(
        qb, kvb, DM, wqb, wkb, DM, 0L, Qh, Kh, DM, 16, 32);
    gemm2<1, 1, 2><<<dim3(512), 256, 0, stream>>>(
        wvb, nullptr, DM, kvb, nullptr, DM, 2097152L, Vt, nullptr, DM, 32, 8);
    attn3<<<dim3(512), 512, 0, stream>>>(Qh, Kh, Vt, kmask, Zt);
    gemm2<1, 1, 1><<<dim3(512), 256, 0, stream>>>(
        Zt, nullptr, T_SZ, wob, nullptr, DM, 0L, out, nullptr, DM, 16, 8);
  } else {
    // conservative path: fits in proven 33.5 MB (weights alias Zt region)
    unsigned short* wqb = ws + 12582912;
    unsigned short* wkb = ws + 13631488;
    unsigned short* wvb = ws + 14680064;
    cvt_w4<<<dim3(256, 3), 256, 0, stream>>>(Wq, Wk, Wv, Wv, wqb, wkb, wvb, wvb, QSCALE);
    gemm2<0, 1, 0><<<dim3(1024), 256, 0, stream>>>(
        q_raw, kv_raw, DM, wqb, wkb, DM, 0L, Qh, Kh, DM, 16, 32);
    gemm2<1, 0, 2><<<dim3(512), 256, 0, stream>>>(
        wvb, nullptr, DM, kv_raw, nullptr, DM, 2097152L, Vt, nullptr, DM, 32, 8);
    attn3<<<dim3(512), 512, 0, stream>>>(Qh, Kh, Vt, kmask, Zt);
    gemm2<1, 0, 1><<<dim3(512), 256, 0, stream>>>(
        Zt, nullptr, T_SZ, Wo, nullptr, DM, 0L, out, nullptr, DM, 16, 8);
  }
}

// Round 15
// 121.728 us; speedup vs baseline: 1.0307x; 1.0307x over previous
//
#include <hip/hip_runtime.h>

#define B_SZ 2
#define T_SZ 2048
#define DM   1024
#define NH   16
#define DH   64

typedef __attribute__((ext_vector_type(8))) short bf16x8;
typedef __attribute__((ext_vector_type(4))) float f32x4;
typedef __attribute__((ext_vector_type(4))) unsigned int u32x4;
typedef __attribute__((ext_vector_type(4))) unsigned short u16x4;

__device__ __forceinline__ unsigned short f2bf(float f) {
  unsigned u = __builtin_bit_cast(unsigned, f);
  u += 0x7FFFu + ((u >> 16) & 1u);
  return (unsigned short)(u >> 16);
}
__device__ __forceinline__ unsigned packbf(float lo, float hi) {
  return (unsigned)f2bf(lo) | ((unsigned)f2bf(hi) << 16);
}

// stage 16 f32 -> 16 bf16 into LDS
__device__ __forceinline__ void stage16(const float* src, unsigned short* dst) {
  const f32x4* ps = (const f32x4*)src;
  f32x4 v0 = ps[0], v1 = ps[1], v2 = ps[2], v3 = ps[3];
  u32x4 w0, w1;
  w0[0] = packbf(v0[0], v0[1]); w0[1] = packbf(v0[2], v0[3]);
  w0[2] = packbf(v1[0], v1[1]); w0[3] = packbf(v1[2], v1[3]);
  w1[0] = packbf(v2[0], v2[1]); w1[1] = packbf(v2[2], v2[3]);
  w1[2] = packbf(v3[0], v3[1]); w1[3] = packbf(v3[2], v3[3]);
  *(u32x4*)dst = w0;
  *(u32x4*)(dst + 8) = w1;
}

// async global->LDS, 16B per lane
__device__ __forceinline__ void gload16(const unsigned short* g, unsigned short* l) {
  __builtin_amdgcn_global_load_lds(
      (const __attribute__((address_space(1))) unsigned int*)(const void*)g,
      (__attribute__((address_space(3))) unsigned int*)(void*)l, 16, 0, 0);
}

__device__ __forceinline__ void cvt16(const float* s, unsigned short* d, float scale) {
  const f32x4* ps = (const f32x4*)s;
  f32x4 v0 = ps[0] * scale, v1 = ps[1] * scale, v2 = ps[2] * scale, v3 = ps[3] * scale;
  u32x4 w0, w1;
  w0[0] = packbf(v0[0], v0[1]); w0[1] = packbf(v0[2], v0[3]);
  w0[2] = packbf(v1[0], v1[1]); w0[3] = packbf(v1[2], v1[3]);
  w1[0] = packbf(v2[0], v2[1]); w1[1] = packbf(v2[2], v2[3]);
  w1[2] = packbf(v3[0], v3[1]); w1[3] = packbf(v3[2], v3[3]);
  *(u32x4*)d = w0;
  *(u32x4*)(d + 8) = w1;
}

// All six f32->bf16 conversions in ONE launch.
__global__ __launch_bounds__(256) void cvt_all(
    const float* __restrict__ wq, const float* __restrict__ wk,
    const float* __restrict__ wv, const float* __restrict__ wo,
    const float* __restrict__ qr, const float* __restrict__ kvr,
    unsigned short* __restrict__ dq, unsigned short* __restrict__ dk,
    unsigned short* __restrict__ dv, unsigned short* __restrict__ dwo,
    unsigned short* __restrict__ dqr, unsigned short* __restrict__ dkvr,
    float qscale) {
  const int bid = blockIdx.x;
  const float* s; unsigned short* d; float sc = 1.0f; int off;
  if (bid < 1024) {
    const int which = bid >> 8; off = bid & 255;
    s = (which == 0) ? wq : (which == 1) ? wk : (which == 2) ? wv : wo;
    d = (which == 0) ? dq : (which == 1) ? dk : (which == 2) ? dv : dwo;
    if (which == 0) sc = qscale;
  } else {
    const int which = (bid - 1024) >> 10; off = (bid - 1024) & 1023;
    s = which ? kvr : qr;
    d = which ? dkvr : dqr;
  }
  const int i = (off * 256 + threadIdx.x) * 16;
  cvt16(s + i, d + i, sc);
}

__global__ __launch_bounds__(256) void cvt_w4(
    const float* __restrict__ s0, const float* __restrict__ s1,
    const float* __restrict__ s2, const float* __restrict__ s3,
    unsigned short* __restrict__ d0, unsigned short* __restrict__ d1,
    unsigned short* __restrict__ d2, unsigned short* __restrict__ d3,
    float qscale) {
  const int y = blockIdx.y;
  const float* s = (y == 0) ? s0 : (y == 1) ? s1 : (y == 2) ? s2 : s3;
  unsigned short* d = (y == 0) ? d0 : (y == 1) ? d1 : (y == 2) ? d2 : d3;
  const float sc = (y == 0) ? qscale : 1.0f;
  const int i = (blockIdx.x * 256 + threadIdx.x) * 16;
  cvt16(s + i, d + i, sc);
}

// C = A * B^T, tile 128x64, BK=32, MFMA 16x16x32 bf16.
// Flat grid + XCD-chunked swizzle.
template<int AMODE, int BMODE, int CMODE>
__global__ __launch_bounds__(256) void gemm2(
    const void* __restrict__ A0, const void* __restrict__ A1, int lda,
    const void* __restrict__ B0, const void* __restrict__ B1, int ldb, long bZ,
    void* __restrict__ C0, void* __restrict__ C1, int K, int nx, int ny) {
  __shared__ unsigned short As[128 * 32];
  __shared__ unsigned short Bs[64 * 32];
  const int tid = threadIdx.x, lane = tid & 63, w = tid >> 6;
  const int wm = w >> 1, wn = w & 1;
  const int l15 = lane & 15, lg = lane >> 4;

  const int cpx = gridDim.x >> 3;
  const int flat = (blockIdx.x & 7) * cpx + (blockIdx.x >> 3);
  const int nbk = flat % nx;
  const int rest = flat / nx;
  const int mbk = rest % ny;
  const int z = rest / ny;
  const int mblk = mbk * 128, nblk = nbk * 64;

  const void* Ap; const void* Bp; void* Cp;
  long aoff = 0; int zb = 0, zs = 0;
  if constexpr (CMODE == 0) {
    Ap = z ? A1 : A0; Bp = z ? B1 : B0; Cp = z ? C1 : C0;
  } else if constexpr (CMODE == 2) {
    Ap = A0; Cp = C0;
    if constexpr (BMODE == 1) Bp = (const void*)((const unsigned short*)B0 + (long)z * bZ);
    else                      Bp = (const void*)((const float*)B0 + (long)z * bZ);
  } else {
    Ap = A0; Bp = B0; Cp = C0;
    zb = z >> 1; zs = z & 1;
    aoff = (long)zb * 2097152 + (long)zs * 1024;
  }

  f32x4 acc[4][2];
#pragma unroll
  for (int i = 0; i < 4; i++)
#pragma unroll
    for (int j = 0; j < 2; j++) acc[i][j] = (f32x4){0.f, 0.f, 0.f, 0.f};

  const int asr = tid >> 1, asc = (tid & 1) * 16;
  const int agr = w * 32 + (lane >> 2), agc = (lane & 3) * 8;
  const int bgr = w * 16 + (lane >> 2), bgc = (lane & 3) * 8;

  for (int k0 = 0; k0 < K; k0 += 32) {
    if constexpr (AMODE == 0) {
      stage16((const float*)Ap + (long)(mblk + asr) * lda + k0 + asc, &As[asr * 32 + asc]);
    } else {
      const unsigned short* Ab = (const unsigned short*)Ap + aoff;
      gload16(Ab + (long)(mblk + agr) * lda + k0 + agc, &As[w * 1024]);
      gload16(Ab + (long)(mblk + agr + 16) * lda + k0 + agc, &As[w * 1024 + 512]);
    }
    if constexpr (BMODE == 0) {
      if (tid < 128)
        stage16((const float*)Bp + (long)(nblk + asr) * ldb + k0 + asc, &Bs[asr * 32 + asc]);
    } else {
      gload16((const unsigned short*)Bp + (long)(nblk + bgr) * ldb + k0 + bgc, &Bs[w * 512]);
    }
    __syncthreads();

    bf16x8 af[4], bfr[2];
#pragma unroll
    for (int mi = 0; mi < 4; mi++)
      af[mi] = *(const bf16x8*)&As[(wm * 64 + mi * 16 + l15) * 32 + lg * 8];
#pragma unroll
    for (int nj = 0; nj < 2; nj++)
      bfr[nj] = *(const bf16x8*)&Bs[(wn * 32 + nj * 16 + l15) * 32 + lg * 8];
#pragma unroll
    for (int mi = 0; mi < 4; mi++)
#pragma unroll
      for (int nj = 0; nj < 2; nj++)
        acc[mi][nj] = __builtin_amdgcn_mfma_f32_16x16x32_bf16(af[mi], bfr[nj], acc[mi][nj], 0, 0, 0);
    __syncthreads();
  }

#pragma unroll
  for (int mi = 0; mi < 4; mi++) {
#pragma unroll
    for (int nj = 0; nj < 2; nj++) {
#pragma unroll
      for (int r = 0; r < 4; r++) {
        const int i = mblk + wm * 64 + mi * 16 + lg * 4 + r;
        const int n = nblk + wn * 32 + nj * 16 + l15;
        const float v = acc[mi][nj][r];
        if constexpr (CMODE == 0) {
          const int b = i >> 11, t = i & 2047, h = n >> 6, d = n & 63;
          ((unsigned short*)Cp)[((long)(b * NH + h) * T_SZ + t) * DH + d] = f2bf(v);
        } else if constexpr (CMODE == 2) {
          ((unsigned short*)Cp)[(long)z * 2097152 + (long)i * 2048 + n] = f2bf(v);
        } else {
          ((float*)Cp)[(long)zb * T_SZ * DM + (long)(2 * i + zs) * DM + n] = v;
        }
      }
    }
  }
}

// Merged QK-projection + Vt-projection, BALANCED per-XCD split:
// each XCD gets 128 QK blocks + 64 Vt blocks (uniform work mix).
// Locality: z = Q on XCDs 0-3, K on 4-7 (weight panel L2-resident per XCD).
__global__ __launch_bounds__(256) void gemm_qkvt(
    const unsigned short* __restrict__ qb, const unsigned short* __restrict__ kvb,
    const unsigned short* __restrict__ wqb, const unsigned short* __restrict__ wkb,
    const unsigned short* __restrict__ wvb,
    unsigned short* __restrict__ Qh, unsigned short* __restrict__ Kh,
    unsigned short* __restrict__ Vt) {
  __shared__ unsigned short As[128 * 32];
  __shared__ unsigned short Bs[64 * 32];
  const int tid = threadIdx.x, lane = tid & 63, w = tid >> 6;
  const int wm = w >> 1, wn = w & 1;
  const int l15 = lane & 15, lg = lane >> 4;

  const int xcd = blockIdx.x & 7;
  const int local = blockIdx.x >> 3;        // 0..191

  const unsigned short* Ap; const unsigned short* Bp;
  int mblk, nblk, z, mode;
  if (local < 128) {
    const int idx = xcd * 128 + local;      // 0..1023
    const int nbk = idx % 16; const int rest = idx / 16;
    const int mbk = rest % 32; z = rest / 32;
    mblk = mbk * 128; nblk = nbk * 64;
    Ap = z ? kvb : qb; Bp = z ? wkb : wqb; mode = 0;
  } else {
    const int idx = xcd * 64 + (local - 128);  // 0..511
    const int nbk = idx % 32; const int rest = idx / 32;
    const int mbk = rest % 8; z = rest / 8;
    mblk = mbk * 128; nblk = nbk * 64;
    Ap = wvb; Bp = kvb + (long)z * 2097152; mode = 1;
  }

  f32x4 acc[4][2];
#pragma unroll
  for (int i = 0; i < 4; i++)
#pragma unroll
    for (int j = 0; j < 2; j++) acc[i][j] = (f32x4){0.f, 0.f, 0.f, 0.f};

  const int agr = w * 32 + (lane >> 2), agc = (lane & 3) * 8;
  const int bgr = w * 16 + (lane >> 2), bgc = (lane & 3) * 8;

  for (int k0 = 0; k0 < DM; k0 += 32) {
    gload16(Ap + (long)(mblk + agr) * DM + k0 + agc, &As[w * 1024]);
    gload16(Ap + (long)(mblk + agr + 16) * DM + k0 + agc, &As[w * 1024 + 512]);
    gload16(Bp + (long)(nblk + bgr) * DM + k0 + bgc, &Bs[w * 512]);
    __syncthreads();

    bf16x8 af[4], bfr[2];
#pragma unroll
    for (int mi = 0; mi < 4; mi++)
      af[mi] = *(const bf16x8*)&As[(wm * 64 + mi * 16 + l15) * 32 + lg * 8];
#pragma unroll
    for (int nj = 0; nj < 2; nj++)
      bfr[nj] = *(const bf16x8*)&Bs[(wn * 32 + nj * 16 + l15) * 32 + lg * 8];
#pragma unroll
    for (int mi = 0; mi < 4; mi++)
#pragma unroll
      for (int nj = 0; nj < 2; nj++)
        acc[mi][nj] = __builtin_amdgcn_mfma_f32_16x16x32_bf16(af[mi], bfr[nj], acc[mi][nj], 0, 0, 0);
    __syncthreads();
  }

  unsigned short* Cp = (mode == 0) ? (z ? Kh : Qh) : Vt;
#pragma unroll
  for (int mi = 0; mi < 4; mi++) {
#pragma unroll
    for (int nj = 0; nj < 2; nj++) {
#pragma unroll
      for (int r = 0; r < 4; r++) {
        const int i = mblk + wm * 64 + mi * 16 + lg * 4 + r;
        const int n = nblk + wn * 32 + nj * 16 + l15;
        const float v = acc[mi][nj][r];
        if (mode == 0) {
          const int b = i >> 11, t = i & 2047, h = n >> 6, d = n & 63;
          Cp[((long)(b * NH + h) * T_SZ + t) * DH + d] = f2bf(v);
        } else {
          Cp[(long)z * 2097152 + (long)i * 2048 + n] = f2bf(v);
        }
      }
    }
  }
}

// Flash attention, causal + kv padding mask. Uniform-17 schedule + LDS bitmask
// + no-max softmax + trunc P->bf16 + row-sum l via MFMA-with-ones.
// (R13/R14 proven body, unchanged.)
__global__ __launch_bounds__(512) void attn3(const unsigned short* __restrict__ Qh,
                                             const unsigned short* __restrict__ Kh,
                                             const unsigned short* __restrict__ Vt,
                                             const int* __restrict__ kmask,
                                             unsigned short* __restrict__ Zt) {
  __shared__ unsigned short lds_kv[2][2][64][72];  // [group][K/V][row][col] 36,864 B
  __shared__ unsigned short lds_p[8][16][72];      // per-wave P buffer      18,432 B
  __shared__ unsigned long long bmask[32];         // per-64-key-tile kv mask
  const int tid = threadIdx.x, lane = tid & 63, w = tid >> 6;
  const int l15 = lane & 15, lg = lane >> 4;
  const int g = w >> 2, sw = w & 3;
  const int wg = blockIdx.x;
  const int xcd = wg & 7, lin = wg >> 3;           // lin in 0..63
  const int bh = xcd * 4 + (lin >> 4);
  const int p = lin & 15;
  const int b = bh >> 4, h = bh & 15;
  const int q0a = (31 - p) * 64;
  const int q0b = p * 64;
  const unsigned short* Qb = Qh + ((long)bh << 17);
  const unsigned short* Kb = Kh + ((long)bh << 17);
  const unsigned short* Vtb = Vt + ((long)(b * DM + h * DH)) * T_SZ;
  const long zbase = (long)(b * DM + h * DH) * T_SZ;

  // bf16 1.0 fragment for row-sum-via-MFMA
  const bf16x8 ones = {0x3F80, 0x3F80, 0x3F80, 0x3F80, 0x3F80, 0x3F80, 0x3F80, 0x3F80};

  // precompute kv-mask bitmask: wave w covers tiles w*4..w*4+3
#pragma unroll
  for (int k = 0; k < 4; k++) {
    const int ti = w * 4 + k;
    const int mk = kmask[b * T_SZ + ti * 64 + lane];
    const unsigned long long bm = __ballot(mk != 0);
    if (lane == 0) bmask[ti] = bm;
  }

  int q0 = g ? q0b : q0a;
  bf16x8 qf0, qf1;
  {
    const int qra = q0 + sw * 16 + l15;
    qf0 = *(const bf16x8*)(Qb + ((long)qra << 6) + lg * 8);
    qf1 = *(const bf16x8*)(Qb + ((long)qra << 6) + 32 + lg * 8);
  }
  int qc0 = q0 + sw * 16 + lg * 4;

  f32x4 o[4];
  float lr[4];
#pragma unroll
  for (int i = 0; i < 4; i++) {
    o[i] = (f32x4){0.f, 0.f, 0.f, 0.f};
    lr[i] = 0.f;
  }

  // staging: quarter = {K_g0, V_g0, K_g1, V_g1}; 2 thr/row, 64 B each
  const int quarter = tid >> 7, sg = quarter >> 1, skv = quarter & 1;
  const int srow = (tid & 127) >> 1;
  const int soff = (tid & 1) * 32;
  const unsigned short* kp = Kb + ((long)srow << 6) + soff;
  const unsigned short* vp = Vtb + (long)srow * T_SZ + soff;

  u32x4 pr0, pr1, pr2, pr3;
  auto issue = [&](int it) {
    int j0s;
    if (sg == 0) j0s = it * 64;
    else j0s = (it <= p) ? it * 64 : ((it < 16) ? (16 + it - p) * 64 : 0);
    const u32x4* s = (const u32x4*)(skv ? (vp + j0s) : (kp + ((long)j0s << 6)));
    pr0 = s[0]; pr1 = s[1]; pr2 = s[2]; pr3 = s[3];
  };

  auto writeZ = [&](const f32x4* oo, const float* ll, int qq) {
    float inv[4];
#pragma unroll
    for (int r = 0; r < 4; r++) inv[r] = (ll[r] > 0.f) ? (1.f / ll[r]) : 0.f;
#pragma unroll
    for (int nb = 0; nb < 4; nb++) {
      u16x4 pk;
#pragma unroll
      for (int r = 0; r < 4; r++) pk[r] = f2bf(oo[nb][r] * inv[r]);
      *(u16x4*)&Zt[zbase + (long)(nb * 16 + l15) * T_SZ + qq] = pk;
    }
  };

  issue(0);
  for (int it = 0; it < 17; ++it) {
    __syncthreads();
    *(u32x4*)&lds_kv[sg][skv][srow][soff] = pr0;
    *(u32x4*)&lds_kv[sg][skv][srow][soff + 8] = pr1;
    *(u32x4*)&lds_kv[sg][skv][srow][soff + 16] = pr2;
    *(u32x4*)&lds_kv[sg][skv][srow][soff + 24] = pr3;
    __syncthreads();
    if (it + 1 < 17) issue(it + 1);

    // group-1 phase switch: seg-b complete -> emit; continue on seg-a tail
    if (g == 1 && it == p + 1) {
      writeZ(o, lr, qc0);
#pragma unroll
      for (int i = 0; i < 4; i++) {
        o[i] = (f32x4){0.f, 0.f, 0.f, 0.f};
        lr[i] = 0.f;
      }
      q0 = q0a;
      const int qra = q0 + sw * 16 + l15;
      qf0 = *(const bf16x8*)(Qb + ((long)qra << 6) + lg * 8);
      qf1 = *(const bf16x8*)(Qb + ((long)qra << 6) + 32 + lg * 8);
      qc0 = q0 + sw * 16 + lg * 4;
    }

    int j0 = it * 64;
    bool valid = true;
    if (g == 1) {
      if (it <= p) j0 = it * 64;
      else if (it < 16) j0 = (16 + it - p) * 64;
      else valid = false;
    }

    if (valid) {
      const unsigned long long kvm = bmask[j0 >> 6];

      f32x4 sa[4];
      __builtin_amdgcn_s_setprio(1);
#pragma unroll
      for (int cb = 0; cb < 4; cb++) {
        bf16x8 kf0 = *(const bf16x8*)&lds_kv[g][0][cb * 16 + l15][lg * 8];
        bf16x8 kf1 = *(const bf16x8*)&lds_kv[g][0][cb * 16 + l15][32 + lg * 8];
        f32x4 t = {0.f, 0.f, 0.f, 0.f};
        t = __builtin_amdgcn_mfma_f32_16x16x32_bf16(qf0, kf0, t, 0, 0, 0);
        t = __builtin_amdgcn_mfma_f32_16x16x32_bf16(qf1, kf1, t, 0, 0, 0);
        sa[cb] = t;
      }
      __builtin_amdgcn_s_setprio(0);

      const bool diag = (j0 == q0);
      if (diag || kvm != ~0ull) {
#pragma unroll
        for (int cb = 0; cb < 4; cb++) {
          const int kk = cb * 16 + l15;
          const bool mk2 = (kvm >> kk) & 1ull;
#pragma unroll
          for (int r = 0; r < 4; r++) {
            const bool ok = mk2 && (!diag || (j0 + kk <= qc0 + r));
            sa[cb][r] = ok ? sa[cb][r] : -1e30f;
          }
        }
      }
      // exp2 + truncating bf16 convert + P store (no max-subtraction needed)
#pragma unroll
      for (int cb = 0; cb < 4; cb++)
#pragma unroll
        for (int r = 0; r < 4; r++) {
          const float pe = __builtin_amdgcn_exp2f(sa[cb][r]);
          lds_p[w][lg * 4 + r][cb * 16 + l15] =
              (unsigned short)(__builtin_bit_cast(unsigned, pe) >> 16);
        }
      bf16x8 pf0 = *(const bf16x8*)&lds_p[w][l15][lg * 8];
      bf16x8 pf1 = *(const bf16x8*)&lds_p[w][l15][32 + lg * 8];

      __builtin_amdgcn_s_setprio(1);
      // l += row-sum(P) via MFMA with ones-B (frees VALU, feeds idle MFMA pipe)
      f32x4 ls = {0.f, 0.f, 0.f, 0.f};
      ls = __builtin_amdgcn_mfma_f32_16x16x32_bf16(pf0, ones, ls, 0, 0, 0);
      ls = __builtin_amdgcn_mfma_f32_16x16x32_bf16(pf1, ones, ls, 0, 0, 0);
#pragma unroll
      for (int nb = 0; nb < 4; nb++) {
        bf16x8 vf0 = *(const bf16x8*)&lds_kv[g][1][nb * 16 + l15][lg * 8];
        bf16x8 vf1 = *(const bf16x8*)&lds_kv[g][1][nb * 16 + l15][32 + lg * 8];
        f32x4 t = o[nb];
        t = __builtin_amdgcn_mfma_f32_16x16x32_bf16(pf0, vf0, t, 0, 0, 0);
        t = __builtin_amdgcn_mfma_f32_16x16x32_bf16(pf1, vf1, t, 0, 0, 0);
        o[nb] = t;
      }
      __builtin_amdgcn_s_setprio(0);
#pragma unroll
      for (int r = 0; r < 4; r++) lr[r] += ls[r];
    }
  }

  // ---- merge seg-a partials: plain sum (no-max softmax) ----
  __syncthreads();
  float* obuf = (float*)&lds_kv[0][0][0][0];   // [4 waves][16 rows][stride 65]
  float* mlb  = obuf + 4 * 16 * 65;            // [4 waves][16] l values
  if (g == 1) {
#pragma unroll
    for (int nb = 0; nb < 4; nb++)
#pragma unroll
      for (int r = 0; r < 4; r++)
        obuf[(sw * 16 + lg * 4 + r) * 65 + nb * 16 + l15] = o[nb][r];
    if (l15 == 0) {
#pragma unroll
      for (int r = 0; r < 4; r++)
        mlb[sw * 16 + lg * 4 + r] = lr[r];
    }
  }
  __syncthreads();
  if (g == 0) {
    float inv[4];
#pragma unroll
    for (int r = 0; r < 4; r++) {
      const float ls2 = lr[r] + mlb[sw * 16 + lg * 4 + r];
      inv[r] = (ls2 > 0.f) ? (1.f / ls2) : 0.f;
    }
#pragma unroll
    for (int nb = 0; nb < 4; nb++) {
      u16x4 pk;
#pragma unroll
      for (int r = 0; r < 4; r++) {
        const float o1 = obuf[(sw * 16 + lg * 4 + r) * 65 + nb * 16 + l15];
        pk[r] = f2bf((o[nb][r] + o1) * inv[r]);
      }
      *(u16x4*)&Zt[zbase + (long)(nb * 16 + l15) * T_SZ + qc0] = pk;
    }
  }
}

extern "C" void kernel_launch(void* const* d_in, const int* in_sizes, int n_in,
                              void* d_out, int out_size, void* d_ws, size_t ws_size,
                              hipStream_t stream) {
  const float* q_raw  = (const float*)d_in[0];
  const float* kv_raw = (const float*)d_in[1];
  const int*   kmask  = (const int*)d_in[2];
  const float* Wq = (const float*)d_in[3];
  const float* Wk = (const float*)d_in[4];
  const float* Wv = (const float*)d_in[5];
  const float* Wo = (const float*)d_in[6];
  float* out = (float*)d_out;

  // 1/sqrt(64) * log2(e): softmax runs in exp2 domain
  const float QSCALE = 0.125f * 1.44269504088896f;

  unsigned short* ws = (unsigned short*)d_ws;
  unsigned short* Qh = ws;                     // [32][2048][64] bf16  8 MB
  unsigned short* Kh = ws + 4194304;           //                      8 MB
  unsigned short* Vt = ws + 8388608;           // [2][1024][2048]      8 MB
  unsigned short* Zt = ws + 12582912;          // [2][1024][2048]      8 MB
  const bool full = ws_size >= (size_t)58720256;

  if (full) {
    unsigned short* wqb = ws + 16777216;
    unsigned short* wkb = ws + 17825792;
    unsigned short* wvb = ws + 18874368;
    unsigned short* wob = ws + 19922944;
    unsigned short* qb  = ws + 20971520;
    unsigned short* kvb = ws + 25165824;
    cvt_all<<<dim3(3072), 256, 0, stream>>>(Wq, Wk, Wv, Wo, q_raw, kv_raw,
                                            wqb, wkb, wvb, wob, qb, kvb, QSCALE);
    gemm_qkvt<<<dim3(1536), 256, 0, stream>>>(qb, kvb, wqb, wkb, wvb, Qh, Kh, Vt);
    attn3<<<dim3(512), 512, 0, stream>>>(Qh, Kh, Vt, kmask, Zt);
    gemm2<1, 1, 1><<<dim3(512), 256, 0, stream>>>(
        Zt, nullptr, T_SZ, wob, nullptr, DM, 0L, out, nullptr, DM, 16, 8);
  } else {
    // conservative path: fits in proven 33.5 MB (weights alias Zt region)
    unsigned short* wqb = ws + 12582912;
    unsigned short* wkb = ws + 13631488;
    unsigned short* wvb = ws + 14680064;
    cvt_w4<<<dim3(256, 3), 256, 0, stream>>>(Wq, Wk, Wv, Wv, wqb, wkb, wvb, wvb, QSCALE);
    gemm2<0, 1, 0><<<dim3(1024), 256, 0, stream>>>(
        q_raw, kv_raw, DM, wqb, wkb, DM, 0L, Qh, Kh, DM, 16, 32);
    gemm2<1, 0, 2><<<dim3(512), 256, 0, stream>>>(
        wvb, nullptr, DM, kv_raw, nullptr, DM, 2097152L, Vt, nullptr, DM, 32, 8);
    attn3<<<dim3(512), 512, 0, stream>>>(Qh, Kh, Vt, kmask, Zt);
    gemm2<1, 0, 1><<<dim3(512), 256, 0, stream>>>(
        Zt, nullptr, T_SZ, Wo, nullptr, DM, 0L, out, nullptr, DM, 16, 8);
  }
}

// Round 16
// 112.255 us; speedup vs baseline: 1.1177x; 1.0844x over previous
//
#include <hip/hip_runtime.h>

#define B_SZ 2
#define T_SZ 2048
#define DM   1024
#define NH   16
#define DH   64

typedef __attribute__((ext_vector_type(8))) short bf16x8;
typedef __attribute__((ext_vector_type(4))) float f32x4;
typedef __attribute__((ext_vector_type(4))) unsigned int u32x4;
typedef __attribute__((ext_vector_type(4))) unsigned short u16x4;

__device__ __forceinline__ unsigned short f2bf(float f) {
  unsigned u = __builtin_bit_cast(unsigned, f);
  u += 0x7FFFu + ((u >> 16) & 1u);
  return (unsigned short)(u >> 16);
}
__device__ __forceinline__ unsigned packbf(float lo, float hi) {
  return (unsigned)f2bf(lo) | ((unsigned)f2bf(hi) << 16);
}

// stage 16 f32 -> 16 bf16 into LDS
__device__ __forceinline__ void stage16(const float* src, unsigned short* dst) {
  const f32x4* ps = (const f32x4*)src;
  f32x4 v0 = ps[0], v1 = ps[1], v2 = ps[2], v3 = ps[3];
  u32x4 w0, w1;
  w0[0] = packbf(v0[0], v0[1]); w0[1] = packbf(v0[2], v0[3]);
  w0[2] = packbf(v1[0], v1[1]); w0[3] = packbf(v1[2], v1[3]);
  w1[0] = packbf(v2[0], v2[1]); w1[1] = packbf(v2[2], v2[3]);
  w1[2] = packbf(v3[0], v3[1]); w1[3] = packbf(v3[2], v3[3]);
  *(u32x4*)dst = w0;
  *(u32x4*)(dst + 8) = w1;
}

// async global->LDS, 16B per lane
__device__ __forceinline__ void gload16(const unsigned short* g, unsigned short* l) {
  __builtin_amdgcn_global_load_lds(
      (const __attribute__((address_space(1))) unsigned int*)(const void*)g,
      (__attribute__((address_space(3))) unsigned int*)(void*)l, 16, 0, 0);
}

__device__ __forceinline__ void cvt16(const float* s, unsigned short* d, float scale) {
  const f32x4* ps = (const f32x4*)s;
  f32x4 v0 = ps[0] * scale, v1 = ps[1] * scale, v2 = ps[2] * scale, v3 = ps[3] * scale;
  u32x4 w0, w1;
  w0[0] = packbf(v0[0], v0[1]); w0[1] = packbf(v0[2], v0[3]);
  w0[2] = packbf(v1[0], v1[1]); w0[3] = packbf(v1[2], v1[3]);
  w1[0] = packbf(v2[0], v2[1]); w1[1] = packbf(v2[2], v2[3]);
  w1[2] = packbf(v3[0], v3[1]); w1[3] = packbf(v3[2], v3[3]);
  *(u32x4*)d = w0;
  *(u32x4*)(d + 8) = w1;
}

// All six f32->bf16 conversions in ONE launch.
__global__ __launch_bounds__(256) void cvt_all(
    const float* __restrict__ wq, const float* __restrict__ wk,
    const float* __restrict__ wv, const float* __restrict__ wo,
    const float* __restrict__ qr, const float* __restrict__ kvr,
    unsigned short* __restrict__ dq, unsigned short* __restrict__ dk,
    unsigned short* __restrict__ dv, unsigned short* __restrict__ dwo,
    unsigned short* __restrict__ dqr, unsigned short* __restrict__ dkvr,
    float qscale) {
  const int bid = blockIdx.x;
  const float* s; unsigned short* d; float sc = 1.0f; int off;
  if (bid < 1024) {
    const int which = bid >> 8; off = bid & 255;
    s = (which == 0) ? wq : (which == 1) ? wk : (which == 2) ? wv : wo;
    d = (which == 0) ? dq : (which == 1) ? dk : (which == 2) ? dv : dwo;
    if (which == 0) sc = qscale;
  } else {
    const int which = (bid - 1024) >> 10; off = (bid - 1024) & 1023;
    s = which ? kvr : qr;
    d = which ? dkvr : dqr;
  }
  const int i = (off * 256 + threadIdx.x) * 16;
  cvt16(s + i, d + i, sc);
}

__global__ __launch_bounds__(256) void cvt_w4(
    const float* __restrict__ s0, const float* __restrict__ s1,
    const float* __restrict__ s2, const float* __restrict__ s3,
    unsigned short* __restrict__ d0, unsigned short* __restrict__ d1,
    unsigned short* __restrict__ d2, unsigned short* __restrict__ d3,
    float qscale) {
  const int y = blockIdx.y;
  const float* s = (y == 0) ? s0 : (y == 1) ? s1 : (y == 2) ? s2 : s3;
  unsigned short* d = (y == 0) ? d0 : (y == 1) ? d1 : (y == 2) ? d2 : d3;
  const float sc = (y == 0) ? qscale : 1.0f;
  const int i = (blockIdx.x * 256 + threadIdx.x) * 16;
  cvt16(s + i, d + i, sc);
}

// C = A * B^T, tile 128x64, BK=64 (two side-by-side BK=32 sub-tiles -> 16
// latency-exposed barrier-pairs instead of 32), MFMA 16x16x32 bf16.
// Flat grid + XCD-chunked swizzle.
template<int AMODE, int BMODE, int CMODE>
__global__ __launch_bounds__(256) void gemm2(
    const void* __restrict__ A0, const void* __restrict__ A1, int lda,
    const void* __restrict__ B0, const void* __restrict__ B1, int ldb, long bZ,
    void* __restrict__ C0, void* __restrict__ C1, int K, int nx, int ny) {
  __shared__ unsigned short As[128 * 64];   // [sub][128][32]
  __shared__ unsigned short Bs[64 * 64];    // [sub][64][32]
  const int tid = threadIdx.x, lane = tid & 63, w = tid >> 6;
  const int wm = w >> 1, wn = w & 1;
  const int l15 = lane & 15, lg = lane >> 4;

  const int cpx = gridDim.x >> 3;
  const int flat = (blockIdx.x & 7) * cpx + (blockIdx.x >> 3);
  const int nbk = flat % nx;
  const int rest = flat / nx;
  const int mbk = rest % ny;
  const int z = rest / ny;
  const int mblk = mbk * 128, nblk = nbk * 64;

  const void* Ap; const void* Bp; void* Cp;
  long aoff = 0; int zb = 0, zs = 0;
  if constexpr (CMODE == 0) {
    Ap = z ? A1 : A0; Bp = z ? B1 : B0; Cp = z ? C1 : C0;
  } else if constexpr (CMODE == 2) {
    Ap = A0; Cp = C0;
    if constexpr (BMODE == 1) Bp = (const void*)((const unsigned short*)B0 + (long)z * bZ);
    else                      Bp = (const void*)((const float*)B0 + (long)z * bZ);
  } else {
    Ap = A0; Bp = B0; Cp = C0;
    zb = z >> 1; zs = z & 1;
    aoff = (long)zb * 2097152 + (long)zs * 1024;
  }

  f32x4 acc[4][2];
#pragma unroll
  for (int i = 0; i < 4; i++)
#pragma unroll
    for (int j = 0; j < 2; j++) acc[i][j] = (f32x4){0.f, 0.f, 0.f, 0.f};

  const int asr = tid >> 1, asc = (tid & 1) * 16;
  const int agr = w * 32 + (lane >> 2), agc = (lane & 3) * 8;
  const int bgr = w * 16 + (lane >> 2), bgc = (lane & 3) * 8;

  for (int k0 = 0; k0 < K; k0 += 64) {
#pragma unroll
    for (int s = 0; s < 2; s++) {
      const int ks = k0 + s * 32;
      if constexpr (AMODE == 0) {
        stage16((const float*)Ap + (long)(mblk + asr) * lda + ks + asc,
                &As[s * 4096 + asr * 32 + asc]);
      } else {
        const unsigned short* Ab = (const unsigned short*)Ap + aoff;
        gload16(Ab + (long)(mblk + agr) * lda + ks + agc, &As[s * 4096 + w * 1024]);
        gload16(Ab + (long)(mblk + agr + 16) * lda + ks + agc, &As[s * 4096 + w * 1024 + 512]);
      }
      if constexpr (BMODE == 0) {
        if (tid < 128)
          stage16((const float*)Bp + (long)(nblk + asr) * ldb + ks + asc,
                  &Bs[s * 2048 + asr * 32 + asc]);
      } else {
        gload16((const unsigned short*)Bp + (long)(nblk + bgr) * ldb + ks + bgc,
                &Bs[s * 2048 + w * 512]);
      }
    }
    __syncthreads();

#pragma unroll
    for (int s = 0; s < 2; s++) {
      bf16x8 af[4], bfr[2];
#pragma unroll
      for (int mi = 0; mi < 4; mi++)
        af[mi] = *(const bf16x8*)&As[s * 4096 + (wm * 64 + mi * 16 + l15) * 32 + lg * 8];
#pragma unroll
      for (int nj = 0; nj < 2; nj++)
        bfr[nj] = *(const bf16x8*)&Bs[s * 2048 + (wn * 32 + nj * 16 + l15) * 32 + lg * 8];
#pragma unroll
      for (int mi = 0; mi < 4; mi++)
#pragma unroll
        for (int nj = 0; nj < 2; nj++)
          acc[mi][nj] = __builtin_amdgcn_mfma_f32_16x16x32_bf16(af[mi], bfr[nj], acc[mi][nj], 0, 0, 0);
    }
    __syncthreads();
  }

#pragma unroll
  for (int mi = 0; mi < 4; mi++) {
#pragma unroll
    for (int nj = 0; nj < 2; nj++) {
#pragma unroll
      for (int r = 0; r < 4; r++) {
        const int i = mblk + wm * 64 + mi * 16 + lg * 4 + r;
        const int n = nblk + wn * 32 + nj * 16 + l15;
        const float v = acc[mi][nj][r];
        if constexpr (CMODE == 0) {
          const int b = i >> 11, t = i & 2047, h = n >> 6, d = n & 63;
          ((unsigned short*)Cp)[((long)(b * NH + h) * T_SZ + t) * DH + d] = f2bf(v);
        } else if constexpr (CMODE == 2) {
          ((unsigned short*)Cp)[(long)z * 2097152 + (long)i * 2048 + n] = f2bf(v);
        } else {
          ((float*)Cp)[(long)zb * T_SZ * DM + (long)(2 * i + zs) * DM + n] = v;
        }
      }
    }
  }
}

// Merged QK-projection + Vt-projection, balanced per-XCD split, BK=64.
__global__ __launch_bounds__(256) void gemm_qkvt(
    const unsigned short* __restrict__ qb, const unsigned short* __restrict__ kvb,
    const unsigned short* __restrict__ wqb, const unsigned short* __restrict__ wkb,
    const unsigned short* __restrict__ wvb,
    unsigned short* __restrict__ Qh, unsigned short* __restrict__ Kh,
    unsigned short* __restrict__ Vt) {
  __shared__ unsigned short As[128 * 64];
  __shared__ unsigned short Bs[64 * 64];
  const int tid = threadIdx.x, lane = tid & 63, w = tid >> 6;
  const int wm = w >> 1, wn = w & 1;
  const int l15 = lane & 15, lg = lane >> 4;

  const int xcd = blockIdx.x & 7;
  const int local = blockIdx.x >> 3;        // 0..191

  const unsigned short* Ap; const unsigned short* Bp;
  int mblk, nblk, z, mode;
  if (local < 128) {
    const int idx = xcd * 128 + local;      // 0..1023
    const int nbk = idx % 16; const int rest = idx / 16;
    const int mbk = rest % 32; z = rest / 32;
    mblk = mbk * 128; nblk = nbk * 64;
    Ap = z ? kvb : qb; Bp = z ? wkb : wqb; mode = 0;
  } else {
    const int idx = xcd * 64 + (local - 128);  // 0..511
    const int nbk = idx % 32; const int rest = idx / 32;
    const int mbk = rest % 8; z = rest / 8;
    mblk = mbk * 128; nblk = nbk * 64;
    Ap = wvb; Bp = kvb + (long)z * 2097152; mode = 1;
  }

  f32x4 acc[4][2];
#pragma unroll
  for (int i = 0; i < 4; i++)
#pragma unroll
    for (int j = 0; j < 2; j++) acc[i][j] = (f32x4){0.f, 0.f, 0.f, 0.f};

  const int agr = w * 32 + (lane >> 2), agc = (lane & 3) * 8;
  const int bgr = w * 16 + (lane >> 2), bgc = (lane & 3) * 8;

  for (int k0 = 0; k0 < DM; k0 += 64) {
#pragma unroll
    for (int s = 0; s < 2; s++) {
      const int ks = k0 + s * 32;
      gload16(Ap + (long)(mblk + agr) * DM + ks + agc, &As[s * 4096 + w * 1024]);
      gload16(Ap + (long)(mblk + agr + 16) * DM + ks + agc, &As[s * 4096 + w * 1024 + 512]);
      gload16(Bp + (long)(nblk + bgr) * DM + ks + bgc, &Bs[s * 2048 + w * 512]);
    }
    __syncthreads();

#pragma unroll
    for (int s = 0; s < 2; s++) {
      bf16x8 af[4], bfr[2];
#pragma unroll
      for (int mi = 0; mi < 4; mi++)
        af[mi] = *(const bf16x8*)&As[s * 4096 + (wm * 64 + mi * 16 + l15) * 32 + lg * 8];
#pragma unroll
      for (int nj = 0; nj < 2; nj++)
        bfr[nj] = *(const bf16x8*)&Bs[s * 2048 + (wn * 32 + nj * 16 + l15) * 32 + lg * 8];
#pragma unroll
      for (int mi = 0; mi < 4; mi++)
#pragma unroll
        for (int nj = 0; nj < 2; nj++)
          acc[mi][nj] = __builtin_amdgcn_mfma_f32_16x16x32_bf16(af[mi], bfr[nj], acc[mi][nj], 0, 0, 0);
    }
    __syncthreads();
  }

  unsigned short* Cp = (mode == 0) ? (z ? Kh : Qh) : Vt;
#pragma unroll
  for (int mi = 0; mi < 4; mi++) {
#pragma unroll
    for (int nj = 0; nj < 2; nj++) {
#pragma unroll
      for (int r = 0; r < 4; r++) {
        const int i = mblk + wm * 64 + mi * 16 + lg * 4 + r;
        const int n = nblk + wn * 32 + nj * 16 + l15;
        const float v = acc[mi][nj][r];
        if (mode == 0) {
          const int b = i >> 11, t = i & 2047, h = n >> 6, d = n & 63;
          Cp[((long)(b * NH + h) * T_SZ + t) * DH + d] = f2bf(v);
        } else {
          Cp[(long)z * 2097152 + (long)i * 2048 + n] = f2bf(v);
        }
      }
    }
  }
}

// Flash attention (R13/R14/R15 proven body, unchanged).
__global__ __launch_bounds__(512) void attn3(const unsigned short* __restrict__ Qh,
                                             const unsigned short* __restrict__ Kh,
                                             const unsigned short* __restrict__ Vt,
                                             const int* __restrict__ kmask,
                                             unsigned short* __restrict__ Zt) {
  __shared__ unsigned short lds_kv[2][2][64][72];
  __shared__ unsigned short lds_p[8][16][72];
  __shared__ unsigned long long bmask[32];
  const int tid = threadIdx.x, lane = tid & 63, w = tid >> 6;
  const int l15 = lane & 15, lg = lane >> 4;
  const int g = w >> 2, sw = w & 3;
  const int wg = blockIdx.x;
  const int xcd = wg & 7, lin = wg >> 3;
  const int bh = xcd * 4 + (lin >> 4);
  const int p = lin & 15;
  const int b = bh >> 4, h = bh & 15;
  const int q0a = (31 - p) * 64;
  const int q0b = p * 64;
  const unsigned short* Qb = Qh + ((long)bh << 17);
  const unsigned short* Kb = Kh + ((long)bh << 17);
  const unsigned short* Vtb = Vt + ((long)(b * DM + h * DH)) * T_SZ;
  const long zbase = (long)(b * DM + h * DH) * T_SZ;

  const bf16x8 ones = {0x3F80, 0x3F80, 0x3F80, 0x3F80, 0x3F80, 0x3F80, 0x3F80, 0x3F80};

#pragma unroll
  for (int k = 0; k < 4; k++) {
    const int ti = w * 4 + k;
    const int mk = kmask[b * T_SZ + ti * 64 + lane];
    const unsigned long long bm = __ballot(mk != 0);
    if (lane == 0) bmask[ti] = bm;
  }

  int q0 = g ? q0b : q0a;
  bf16x8 qf0, qf1;
  {
    const int qra = q0 + sw * 16 + l15;
    qf0 = *(const bf16x8*)(Qb + ((long)qra << 6) + lg * 8);
    qf1 = *(const bf16x8*)(Qb + ((long)qra << 6) + 32 + lg * 8);
  }
  int qc0 = q0 + sw * 16 + lg * 4;

  f32x4 o[4];
  float lr[4];
#pragma unroll
  for (int i = 0; i < 4; i++) {
    o[i] = (f32x4){0.f, 0.f, 0.f, 0.f};
    lr[i] = 0.f;
  }

  const int quarter = tid >> 7, sg = quarter >> 1, skv = quarter & 1;
  const int srow = (tid & 127) >> 1;
  const int soff = (tid & 1) * 32;
  const unsigned short* kp = Kb + ((long)srow << 6) + soff;
  const unsigned short* vp = Vtb + (long)srow * T_SZ + soff;

  u32x4 pr0, pr1, pr2, pr3;
  auto issue = [&](int it) {
    int j0s;
    if (sg == 0) j0s = it * 64;
    else j0s = (it <= p) ? it * 64 : ((it < 16) ? (16 + it - p) * 64 : 0);
    const u32x4* s = (const u32x4*)(skv ? (vp + j0s) : (kp + ((long)j0s << 6)));
    pr0 = s[0]; pr1 = s[1]; pr2 = s[2]; pr3 = s[3];
  };

  auto writeZ = [&](const f32x4* oo, const float* ll, int qq) {
    float inv[4];
#pragma unroll
    for (int r = 0; r < 4; r++) inv[r] = (ll[r] > 0.f) ? (1.f / ll[r]) : 0.f;
#pragma unroll
    for (int nb = 0; nb < 4; nb++) {
      u16x4 pk;
#pragma unroll
      for (int r = 0; r < 4; r++) pk[r] = f2bf(oo[nb][r] * inv[r]);
      *(u16x4*)&Zt[zbase + (long)(nb * 16 + l15) * T_SZ + qq] = pk;
    }
  };

  issue(0);
  for (int it = 0; it < 17; ++it) {
    __syncthreads();
    *(u32x4*)&lds_kv[sg][skv][srow][soff] = pr0;
    *(u32x4*)&lds_kv[sg][skv][srow][soff + 8] = pr1;
    *(u32x4*)&lds_kv[sg][skv][srow][soff + 16] = pr2;
    *(u32x4*)&lds_kv[sg][skv][srow][soff + 24] = pr3;
    __syncthreads();
    if (it + 1 < 17) issue(it + 1);

    if (g == 1 && it == p + 1) {
      writeZ(o, lr, qc0);
#pragma unroll
      for (int i = 0; i < 4; i++) {
        o[i] = (f32x4){0.f, 0.f, 0.f, 0.f};
        lr[i] = 0.f;
      }
      q0 = q0a;
      const int qra = q0 + sw * 16 + l15;
      qf0 = *(const bf16x8*)(Qb + ((long)qra << 6) + lg * 8);
      qf1 = *(const bf16x8*)(Qb + ((long)qra << 6) + 32 + lg * 8);
      qc0 = q0 + sw * 16 + lg * 4;
    }

    int j0 = it * 64;
    bool valid = true;
    if (g == 1) {
      if (it <= p) j0 = it * 64;
      else if (it < 16) j0 = (16 + it - p) * 64;
      else valid = false;
    }

    if (valid) {
      const unsigned long long kvm = bmask[j0 >> 6];

      f32x4 sa[4];
      __builtin_amdgcn_s_setprio(1);
#pragma unroll
      for (int cb = 0; cb < 4; cb++) {
        bf16x8 kf0 = *(const bf16x8*)&lds_kv[g][0][cb * 16 + l15][lg * 8];
        bf16x8 kf1 = *(const bf16x8*)&lds_kv[g][0][cb * 16 + l15][32 + lg * 8];
        f32x4 t = {0.f, 0.f, 0.f, 0.f};
        t = __builtin_amdgcn_mfma_f32_16x16x32_bf16(qf0, kf0, t, 0, 0, 0);
        t = __builtin_amdgcn_mfma_f32_16x16x32_bf16(qf1, kf1, t, 0, 0, 0);
        sa[cb] = t;
      }
      __builtin_amdgcn_s_setprio(0);

      const bool diag = (j0 == q0);
      if (diag || kvm != ~0ull) {
#pragma unroll
        for (int cb = 0; cb < 4; cb++) {
          const int kk = cb * 16 + l15;
          const bool mk2 = (kvm >> kk) & 1ull;
#pragma unroll
          for (int r = 0; r < 4; r++) {
            const bool ok = mk2 && (!diag || (j0 + kk <= qc0 + r));
            sa[cb][r] = ok ? sa[cb][r] : -1e30f;
          }
        }
      }
#pragma unroll
      for (int cb = 0; cb < 4; cb++)
#pragma unroll
        for (int r = 0; r < 4; r++) {
          const float pe = __builtin_amdgcn_exp2f(sa[cb][r]);
          lds_p[w][lg * 4 + r][cb * 16 + l15] =
              (unsigned short)(__builtin_bit_cast(unsigned, pe) >> 16);
        }
      bf16x8 pf0 = *(const bf16x8*)&lds_p[w][l15][lg * 8];
      bf16x8 pf1 = *(const bf16x8*)&lds_p[w][l15][32 + lg * 8];

      __builtin_amdgcn_s_setprio(1);
      f32x4 ls = {0.f, 0.f, 0.f, 0.f};
      ls = __builtin_amdgcn_mfma_f32_16x16x32_bf16(pf0, ones, ls, 0, 0, 0);
      ls = __builtin_amdgcn_mfma_f32_16x16x32_bf16(pf1, ones, ls, 0, 0, 0);
#pragma unroll
      for (int nb = 0; nb < 4; nb++) {
        bf16x8 vf0 = *(const bf16x8*)&lds_kv[g][1][nb * 16 + l15][lg * 8];
        bf16x8 vf1 = *(const bf16x8*)&lds_kv[g][1][nb * 16 + l15][32 + lg * 8];
        f32x4 t = o[nb];
        t = __builtin_amdgcn_mfma_f32_16x16x32_bf16(pf0, vf0, t, 0, 0, 0);
        t = __builtin_amdgcn_mfma_f32_16x16x32_bf16(pf1, vf1, t, 0, 0, 0);
        o[nb] = t;
      }
      __builtin_amdgcn_s_setprio(0);
#pragma unroll
      for (int r = 0; r < 4; r++) lr[r] += ls[r];
    }
  }

  __syncthreads();
  float* obuf = (float*)&lds_kv[0][0][0][0];
  float* mlb  = obuf + 4 * 16 * 65;
  if (g == 1) {
#pragma unroll
    for (int nb = 0; nb < 4; nb++)
#pragma unroll
      for (int r = 0; r < 4; r++)
        obuf[(sw * 16 + lg * 4 + r) * 65 + nb * 16 + l15] = o[nb][r];
    if (l15 == 0) {
#pragma unroll
      for (int r = 0; r < 4; r++)
        mlb[sw * 16 + lg * 4 + r] = lr[r];
    }
  }
  __syncthreads();
  if (g == 0) {
    float inv[4];
#pragma unroll
    for (int r = 0; r < 4; r++) {
      const float ls2 = lr[r] + mlb[sw * 16 + lg * 4 + r];
      inv[r] = (ls2 > 0.f) ? (1.f / ls2) : 0.f;
    }
#pragma unroll
    for (int nb = 0; nb < 4; nb++) {
      u16x4 pk;
#pragma unroll
      for (int r = 0; r < 4; r++) {
        const float o1 = obuf[(sw * 16 + lg * 4 + r) * 65 + nb * 16 + l15];
        pk[r] = f2bf((o[nb][r] + o1) * inv[r]);
      }
      *(u16x4*)&Zt[zbase + (long)(nb * 16 + l15) * T_SZ + qc0] = pk;
    }
  }
}

extern "C" void kernel_launch(void* const* d_in, const int* in_sizes, int n_in,
                              void* d_out, int out_size, void* d_ws, size_t ws_size,
                              hipStream_t stream) {
  const float* q_raw  = (const float*)d_in[0];
  const float* kv_raw = (const float*)d_in[1];
  const int*   kmask  = (const int*)d_in[2];
  const float* Wq = (const float*)d_in[3];
  const float* Wk = (const float*)d_in[4];
  const float* Wv = (const float*)d_in[5];
  const float* Wo = (const float*)d_in[6];
  float* out = (float*)d_out;

  const float QSCALE = 0.125f * 1.44269504088896f;

  unsigned short* ws = (unsigned short*)d_ws;
  unsigned short* Qh = ws;
  unsigned short* Kh = ws + 4194304;
  unsigned short* Vt = ws + 8388608;
  unsigned short* Zt = ws + 12582912;
  const bool full = ws_size >= (size_t)58720256;

  if (full) {
    unsigned short* wqb = ws + 16777216;
    unsigned short* wkb = ws + 17825792;
    unsigned short* wvb = ws + 18874368;
    unsigned short* wob = ws + 19922944;
    unsigned short* qb  = ws + 20971520;
    unsigned short* kvb = ws + 25165824;
    cvt_all<<<dim3(3072), 256, 0, stream>>>(Wq, Wk, Wv, Wo, q_raw, kv_raw,
                                            wqb, wkb, wvb, wob, qb, kvb, QSCALE);
    gemm_qkvt<<<dim3(1536), 256, 0, stream>>>(qb, kvb, wqb, wkb, wvb, Qh, Kh, Vt);
    attn3<<<dim3(512), 512, 0, stream>>>(Qh, Kh, Vt, kmask, Zt);
    gemm2<1, 1, 1><<<dim3(512), 256, 0, stream>>>(
        Zt, nullptr, T_SZ, wob, nullptr, DM, 0L, out, nullptr, DM, 16, 8);
  } else {
    unsigned short* wqb = ws + 12582912;
    unsigned short* wkb = ws + 13631488;
    unsigned short* wvb = ws + 14680064;
    cvt_w4<<<dim3(256, 3), 256, 0, stream>>>(Wq, Wk, Wv, Wv, wqb, wkb, wvb, wvb, QSCALE);
    gemm2<0, 1, 0><<<dim3(1024), 256, 0, stream>>>(
        q_raw, kv_raw, DM, wqb, wkb, DM, 0L, Qh, Kh, DM, 16, 32);
    gemm2<1, 0, 2><<<dim3(512), 256, 0, stream>>>(
        wvb, nullptr, DM, kv_raw, nullptr, DM, 2097152L, Vt, nullptr, DM, 32, 8);
    attn3<<<dim3(512), 512, 0, stream>>>(Qh, Kh, Vt, kmask, Zt);
    gemm2<1, 0, 1><<<dim3(512), 256, 0, stream>>>(
        Zt, nullptr, T_SZ, Wo, nullptr, DM, 0L, out, nullptr, DM, 16, 8);
  }
}